// Round 18
// baseline (263.725 us; speedup 1.0000x reference)
//
#include <hip/hip_runtime.h>
#include <hip/hip_bf16.h>

// Transformer-XL relative multihead attention, MI355X/gfx950.
// B=2, QLEN=1024, MLEN=1024, KLEN=2048, C=1024, H=16, DK=64.
//
// Round 18 = round 17 with attn_fused fused to a SINGLE pass per chunk:
//   per 128-col chunk: stage K+BD+V(c+1) -> vmcnt(5) -> barrier ->
//   QK (16x16x32) + exp -> PV on UNNORMALIZED p via 16x16x16 MFMA whose
//   A-frag layout equals pst's register layout (no pt transpose) -> barrier.
//   16 phases (was 32), aw + cv normalization in barrier-free epilogue.
//   LDS 80KB: K dbuf @0 (2x16K), BD dbuf @32768 (2x8K), V dbuf @49152 (2x16K);
//   post-loop: cvl @0, ssum @33792.
//
// rel_shift closed form (d = j-i):
//   d<=1024 : BD = qv_i  . p_{d+1023}   (main)
//   d==1025 : 0                          (never written; masked at read)
//   d>=1026 : BD = qv_{i+1} . p_{d-1026} (wrap)

typedef __hip_bfloat16 bf16;
typedef __attribute__((ext_vector_type(8))) short bf16x8v;
typedef __attribute__((ext_vector_type(4))) short bf16x4v;
typedef __attribute__((ext_vector_type(4))) float f32x4;

#define MFMA16(A, B, C) __builtin_amdgcn_mfma_f32_16x16x32_bf16(A, B, C, 0, 0, 0)
#define MFMA16H(A, B, C) __builtin_amdgcn_mfma_f32_16x16x16bf16_1k(A, B, C, 0, 0, 0)

#define QL 1024
#define KL 2048
#define NH 16
#define DKD 64
#define CD 1024

static __device__ __forceinline__ unsigned short f2bf(float x) {
  __hip_bfloat16 h = __float2bfloat16(x);
  return __builtin_bit_cast(unsigned short, h);
}
static __device__ __forceinline__ float bf2f(unsigned short u) {
  return __builtin_bit_cast(float, (unsigned)u << 16);
}

typedef const __attribute__((address_space(1))) void* gptr_t;
typedef __attribute__((address_space(3))) void* sptr_t;

// ---------------- merged cast kernel ----------------

__global__ void cast_all(const float* __restrict__ key, const float* __restrict__ pos,
                         const float* __restrict__ wk, const float* __restrict__ wv,
                         const float* __restrict__ wq, const float* __restrict__ wp,
                         const float* __restrict__ wo,
                         bf16* __restrict__ keyb, bf16* __restrict__ qsrc,
                         bf16* __restrict__ posb, bf16* __restrict__ wkvb,
                         bf16* __restrict__ wqpb, bf16* __restrict__ wob) {
  const int bid = blockIdx.x;
  if (bid < 4096) {
    int i = (bid * 256 + threadIdx.x) * 4;
    float4 v = *(const float4*)(key + i);
    ushort4 o;
    o.x = f2bf(v.x); o.y = f2bf(v.y); o.z = f2bf(v.z); o.w = f2bf(v.w);
    *(ushort4*)((unsigned short*)keyb + i) = o;
    int row = i >> 10;
    int col = i & (CD - 1);
    int r2 = row & (KL - 1);
    if (r2 >= QL) {
      int qrow = (row >> 11) * QL + (r2 - QL);
      *(ushort4*)((unsigned short*)qsrc + (size_t)qrow * CD + col) = o;
    }
    return;
  }
  const int mb = bid - 4096;
  const float* src;
  bf16* dst;
  int cb;
  if (mb < 2048)      { src = pos; dst = posb;           cb = mb; }
  else if (mb < 3072) { src = wk;  dst = wkvb;           cb = mb - 2048; }
  else if (mb < 4096) { src = wv;  dst = wkvb + (1<<20); cb = mb - 3072; }
  else if (mb < 5120) { src = wq;  dst = wqpb;           cb = mb - 4096; }
  else if (mb < 6144) { src = wp;  dst = wqpb + (1<<20); cb = mb - 5120; }
  else                { src = wo;  dst = wob;            cb = mb - 6144; }
  int i = cb * 1024 + threadIdx.x * 4;
  float4 v = *(const float4*)(src + i);
  ushort4 o;
  o.x = f2bf(v.x); o.y = f2bf(v.y); o.z = f2bf(v.z); o.w = f2bf(v.w);
  *(ushort4*)((unsigned short*)dst + i) = o;
}

// ---------------- GEMM: C = A @ Bt^T, global_load_lds staging ----------------
// MODE 1: f32 row-major out (O1), stride N
// MODE 4: kv merged: n0<1024 -> Kp[bh][KL][64] (O1); else Vt[bh][dk][KL] (O2)
// MODE 5: z=0: qsrc -> qu/qvb with biases; z=1: posb -> Pbuf (O3)

template <int MODE>
__global__ __launch_bounds__(256) void gemm_bt(
    const bf16* __restrict__ Ain, const bf16* __restrict__ A2,
    const bf16* __restrict__ Btin,
    void* __restrict__ O1, void* __restrict__ O2, void* __restrict__ O3,
    const float* __restrict__ bias1, const float* __restrict__ bias2,
    int M, int N, int K) {
  __shared__ __align__(16) bf16 As[128 * 32];
  __shared__ __align__(16) bf16 Bs[128 * 32];
  const int tid = threadIdx.x;
  const int lane = tid & 63;
  const int wid = tid >> 6;
  const int wr = wid >> 1, wc = wid & 1;
  const int lrow = lane & 15, lk = lane >> 4;
  const int m0 = blockIdx.x * 128, n0 = blockIdx.y * 128;

  const bf16* A = Ain;
  const bf16* Bt = Btin;
  if (MODE == 5) {
    if (blockIdx.z) { A = A2; Bt = Btin + (size_t)(1 << 20); }
  }

  f32x4 acc[4][4];
#pragma unroll
  for (int i = 0; i < 4; i++)
#pragma unroll
    for (int j = 0; j < 4; j++) acc[i][j] = (f32x4){0.f, 0.f, 0.f, 0.f};

  for (int k0 = 0; k0 < K; k0 += 32) {
#pragma unroll
    for (int st = 0; st < 2; ++st) {
      int c = st * 256 + tid;
      __builtin_amdgcn_global_load_lds(
          (gptr_t)(A + (size_t)(m0 + (c >> 2)) * K + k0 + (c & 3) * 8),
          (sptr_t)(As + c * 8), 16, 0, 0);
      __builtin_amdgcn_global_load_lds(
          (gptr_t)(Bt + (size_t)(n0 + (c >> 2)) * K + k0 + (c & 3) * 8),
          (sptr_t)(Bs + c * 8), 16, 0, 0);
    }
    __syncthreads();
    bf16x8v aF[4], bF[4];
#pragma unroll
    for (int s = 0; s < 4; s++) {
      aF[s] = *(const bf16x8v*)(As + (wr * 64 + s * 16 + lrow) * 32 + lk * 8);
      bF[s] = *(const bf16x8v*)(Bs + (wc * 64 + s * 16 + lrow) * 32 + lk * 8);
    }
#pragma unroll
    for (int i = 0; i < 4; i++)
#pragma unroll
      for (int j = 0; j < 4; j++) acc[i][j] = MFMA16(aF[i], bF[j], acc[i][j]);
    __syncthreads();
  }

  const int row0 = m0 + wr * 64 + lk * 4;
  const int col0 = n0 + wc * 64 + lrow;

  if (MODE == 1) {
    float* C = (float*)O1;
#pragma unroll
    for (int i = 0; i < 4; i++)
#pragma unroll
      for (int j = 0; j < 4; j++) {
        int r = row0 + i * 16, c = col0 + j * 16;
#pragma unroll
        for (int q = 0; q < 4; q++) C[(size_t)(r + q) * N + c] = acc[i][j][q];
      }
  } else if (MODE == 4) {
    if (n0 < 1024) {
      // K -> Kp[bh][j][64]
      bf16* C = (bf16*)O1;
#pragma unroll
      for (int i = 0; i < 4; i++)
#pragma unroll
        for (int j = 0; j < 4; j++) {
          int c = col0 + j * 16;
          const int hh = c >> 6, dd = c & 63;
#pragma unroll
          for (int q = 0; q < 4; q++) {
            int m = row0 + i * 16 + q;
            const int bb = m >> 11, jj = m & (KL - 1);
            C[((size_t)(bb * NH + hh) * KL + jj) * DKD + dd] = __float2bfloat16(acc[i][j][q]);
          }
        }
    } else {
      unsigned short* C = (unsigned short*)O2;  // Vt[(b*NH+h)*DKD+dd][KL]
#pragma unroll
      for (int i = 0; i < 4; i++)
#pragma unroll
        for (int j = 0; j < 4; j++) {
          int m = row0 + i * 16;
          int c = col0 + j * 16 - 1024;
          int bb = m >> 11;
          int jj = m & (KL - 1);
          int bhh = bb * NH + (c >> 6);
          int dd = c & (DKD - 1);
          ushort4 o;
          o.x = f2bf(acc[i][j][0]); o.y = f2bf(acc[i][j][1]);
          o.z = f2bf(acc[i][j][2]); o.w = f2bf(acc[i][j][3]);
          *(ushort4*)(C + (size_t)(bhh * DKD + dd) * KL + jj) = o;
        }
    }
  } else {  // MODE 5
    if (blockIdx.z == 0) {
      bf16* C1 = (bf16*)O1;
      bf16* C2 = (bf16*)O2;
#pragma unroll
      for (int i = 0; i < 4; i++)
#pragma unroll
        for (int j = 0; j < 4; j++) {
          int r = row0 + i * 16, c = col0 + j * 16;
          float b1 = bias1[c], b2 = bias2[c];
#pragma unroll
          for (int q = 0; q < 4; q++) {
            float v = acc[i][j][q];
            C1[(size_t)(r + q) * CD + c] = __float2bfloat16(v + b1);
            C2[(size_t)(r + q) * CD + c] = __float2bfloat16(v + b2);
          }
        }
    } else {
      bf16* C = (bf16*)O3;
#pragma unroll
      for (int i = 0; i < 4; i++)
#pragma unroll
        for (int j = 0; j < 4; j++) {
          int r = row0 + i * 16, c = col0 + j * 16;
#pragma unroll
          for (int q = 0; q < 4; q++) C[(size_t)(r + q) * CD + c] = __float2bfloat16(acc[i][j][q]);
        }
    }
  }
}

// ---------------- BD gemm with shifted write ----------------
// BDfull[i,c] = qv[b,i,h,:] . Pb[c,h,:]  (K=64). grid (8, 16, 32), block 256.

__global__ __launch_bounds__(256) void bd_gemm(
    const bf16* __restrict__ qvb, const bf16* __restrict__ Pbuf,
    unsigned short* __restrict__ BDsh) {
  __shared__ __align__(16) bf16 As[128 * 32];
  __shared__ __align__(16) bf16 Bs[128 * 32];
  const int tid = threadIdx.x;
  const int lane = tid & 63;
  const int wid = tid >> 6;
  const int wr = wid >> 1, wc = wid & 1;
  const int lrow = lane & 15, lk = lane >> 4;
  const int m0 = blockIdx.x * 128, n0 = blockIdx.y * 128;
  const int bh = blockIdx.z, b = bh >> 4, h = bh & 15;

  const bf16* A = qvb + (size_t)(b * QL + m0) * CD + h * DKD;
  const bf16* Bt = Pbuf + (size_t)n0 * CD + h * DKD;

  f32x4 acc[4][4];
#pragma unroll
  for (int i = 0; i < 4; i++)
#pragma unroll
    for (int j = 0; j < 4; j++) acc[i][j] = (f32x4){0.f, 0.f, 0.f, 0.f};

#pragma unroll
  for (int k0 = 0; k0 < 64; k0 += 32) {
#pragma unroll
    for (int st = 0; st < 2; ++st) {
      int c = st * 256 + tid;
      __builtin_amdgcn_global_load_lds(
          (gptr_t)(A + (size_t)(c >> 2) * CD + k0 + (c & 3) * 8),
          (sptr_t)(As + c * 8), 16, 0, 0);
      __builtin_amdgcn_global_load_lds(
          (gptr_t)(Bt + (size_t)(c >> 2) * CD + k0 + (c & 3) * 8),
          (sptr_t)(Bs + c * 8), 16, 0, 0);
    }
    __syncthreads();
    bf16x8v aF[4], bF[4];
#pragma unroll
    for (int s = 0; s < 4; s++) {
      aF[s] = *(const bf16x8v*)(As + (wr * 64 + s * 16 + lrow) * 32 + lk * 8);
      bF[s] = *(const bf16x8v*)(Bs + (wc * 64 + s * 16 + lrow) * 32 + lk * 8);
    }
#pragma unroll
    for (int i = 0; i < 4; i++)
#pragma unroll
      for (int j = 0; j < 4; j++) acc[i][j] = MFMA16(aF[i], bF[j], acc[i][j]);
    __syncthreads();
  }

  unsigned short* out = BDsh + (size_t)bh * QL * KL;
  const int row0 = m0 + wr * 64 + lk * 4;
  const int col0 = n0 + wc * 64 + lrow;
#pragma unroll
  for (int i = 0; i < 4; i++)
#pragma unroll
    for (int j = 0; j < 4; j++) {
      const int cg = col0 + j * 16;
#pragma unroll
      for (int q = 0; q < 4; q++) {
        const int il = row0 + i * 16 + q;  // 0..1023
        const int thr = 1023 - il;
        unsigned short val = f2bf(acc[i][j][q]);
        if (cg >= thr) {
          out[(size_t)il * KL + (cg - thr)] = val;            // d <= 1024
        } else if (il >= 1) {
          out[(size_t)(il - 1) * KL + il + 1025 + cg] = val;  // d >= 1026
        }
      }
    }
}

// ---------------- fused score + softmax + aw + PV kernel (single pass) ----------------
// 1-D grid 1024, XCD-aware decode. Block 512 = 8 waves = 2 tile-groups of 4;
// tile-group t handles rows [pair*32 + t*16, +16). Per 128-col chunk, wave wq
// owns cols [wq*32,(wq+1)*32). One pass: QK + exp + PV(unnormalized, 16x16x16
// MFMA, A-frag = pst registers). aw + cv normalized in epilogue.
// LDS = 81920 B: K dbuf @0 (2x16384), BD dbuf @32768 (2x8192),
// V dbuf @49152 (2x16384); post-loop: cvl @0 (33792), ssum @33792 (512).

__global__ __launch_bounds__(512) void attn_fused(
    const bf16* __restrict__ qu, const unsigned short* __restrict__ Kp,
    const unsigned short* __restrict__ BDsh, const unsigned short* __restrict__ Vt,
    float* __restrict__ aw, bf16* __restrict__ cvb) {
  __shared__ __align__(16) char smraw[81920];
  float* cvl = (float*)smraw;              // [2][4][16][66] = 33792 B (post-loop)
  float* ssum = (float*)(smraw + 33792);   // [8][16] (post-loop)

  const int bid = blockIdx.x;
  const int xcd = bid & 7;
  const int kk = bid >> 3;  // 0..127
  const int bh = xcd * 4 + (kk >> 5);
  const int pair = kk & 31;
  const int i0p = pair * 32;
  const int b = bh >> 4, h = bh & 15;
  const int tid = threadIdx.x;
  const int lane = tid & 63, wid = tid >> 6;
  const int tile = wid >> 2, wq = wid & 3;
  const int lrow = lane & 15, lk = lane >> 4;
  const int i0 = i0p + tile * 16;
  const int irow = i0 + lrow;

  const size_t qoff = (size_t)(b * QL + irow) * CD + h * DKD + lk * 8;
  const bf16x8v quF0 = *(const bf16x8v*)(qu + qoff);
  const bf16x8v quF1 = *(const bf16x8v*)(qu + qoff + 32);

  const unsigned short* Kph = Kp + (size_t)bh * KL * DKD;             // [j][64]
  const unsigned short* BDrow = BDsh + (size_t)(bh * QL + i0p) * KL;  // 32 rows
  const unsigned short* Vth = Vt + (size_t)bh * DKD * KL;             // [dk][KL]
  float* awp = aw + (size_t)(bh * QL + irow) * KL;

  bf16x4v pst[32];
  float lacc = 0.f;

  // stage for chunk cc: K (2 loads) + BD (1) + V (2) = 5 loads/thread
  auto stageA = [&](int cc, int bsel) {
#pragma unroll
    for (int st = 0; st < 2; ++st) {
      const int pos = (st * 512 + tid) * 16;
      const int krow = pos >> 7;
      const int kb = (pos & 127) ^ ((krow & 7) << 4);
      __builtin_amdgcn_global_load_lds(
          (gptr_t)(Kph + (size_t)(cc * 128 + krow) * DKD + (kb >> 1)),
          (sptr_t)(smraw + bsel * 16384 + pos), 16, 0, 0);
    }
    {
      const int pos = tid * 16;
      const int brow = pos >> 8;  // 0..31
      const int bb2 = (pos & 255) ^ ((brow & 7) << 4);
      __builtin_amdgcn_global_load_lds(
          (gptr_t)(BDrow + (size_t)brow * KL + cc * 128 + (bb2 >> 1)),
          (sptr_t)(smraw + 32768 + bsel * 8192 + pos), 16, 0, 0);
    }
#pragma unroll
    for (int st = 0; st < 2; ++st) {
      const int pos = (st * 512 + tid) * 16;
      const int vrow = pos >> 8;
      const int vb = (pos & 255) ^ ((vrow & 7) << 4);
      __builtin_amdgcn_global_load_lds(
          (gptr_t)(Vth + (size_t)vrow * KL + cc * 128 + (vb >> 1)),
          (sptr_t)(smraw + 49152 + bsel * 16384 + pos), 16, 0, 0);
    }
  };

  f32x4 cvacc[4];
#pragma unroll
  for (int dd = 0; dd < 4; ++dd) cvacc[dd] = (f32x4){0.f, 0.f, 0.f, 0.f};

  // ---- single-pass chunk loop ----
  stageA(0, 0);
#pragma unroll
  for (int c = 0; c < 16; ++c) {
    const int cur = c & 1;
    if (c < 15) {
      stageA(c + 1, cur ^ 1);
      asm volatile("s_waitcnt vmcnt(5)" ::: "memory");
    } else {
      asm volatile("s_waitcnt vmcnt(0)" ::: "memory");
    }
    __builtin_amdgcn_sched_barrier(0);
    __builtin_amdgcn_s_barrier();

    const char* Kc = (const char*)smraw + cur * 16384;
    const char* BDc = (const char*)smraw + 32768 + cur * 8192;
    const char* Vc = (const char*)smraw + 49152 + cur * 16384;

    // QK + exp -> pst (unnormalized p, bf16)
#pragma unroll
    for (int s2 = 0; s2 < 2; ++s2) {
      const int jloc = wq * 32 + s2 * 16 + lrow;
      const int sw = (jloc & 7) << 4;
      const bf16x8v kF0 = *(const bf16x8v*)(Kc + jloc * 128 + ((lk * 16) ^ sw));
      const bf16x8v kF1 = *(const bf16x8v*)(Kc + jloc * 128 + ((64 + lk * 16) ^ sw));
      f32x4 ac = (f32x4){0.f, 0.f, 0.f, 0.f};
      __builtin_amdgcn_s_setprio(1);
      ac = MFMA16(kF0, quF0, ac);  // swapped: out row = j-local, col = i-local
      ac = MFMA16(kF1, quF1, ac);
      __builtin_amdgcn_s_setprio(0);

      const int bdb = (tile * 16 + lrow) * 256 +
                      ((wq * 64 + s2 * 32 + lk * 8) ^ ((lrow & 7) << 4));
      const ushort4 bd4 = *(const ushort4*)(BDc + bdb);
      const unsigned short* bdp = (const unsigned short*)&bd4;
      bf16x4v pb;
      unsigned short* pp = (unsigned short*)&pb;
#pragma unroll
      for (int q = 0; q < 4; ++q) {
        const int jcol = c * 128 + wq * 32 + s2 * 16 + lk * 4 + q;
        const float bd = (jcol - irow == 1025) ? 0.f : bf2f(bdp[q]);
        const float pu = __expf((ac[q] + bd) * 0.125f);
        lacc += pu;
        pp[q] = f2bf(pu);
      }
      pst[c * 2 + s2] = pb;
    }

    // PV on unnormalized p: 16x16x16 MFMA, A-frag = pst registers directly.
    __builtin_amdgcn_s_setprio(1);
#pragma unroll
    for (int dd = 0; dd < 4; ++dd) {
      const int vr = dd * 16 + lrow;
#pragma unroll
      for (int s2 = 0; s2 < 2; ++s2) {
        const bf16x4v vF = *(const bf16x4v*)(
            Vc + vr * 256 + ((wq * 64 + s2 * 32 + lk * 8) ^ ((vr & 7) << 4)));
        cvacc[dd] = MFMA16H(pst[c * 2 + s2], vF, cvacc[dd]);
      }
    }
    __builtin_amdgcn_s_setprio(0);
    __builtin_amdgcn_s_barrier();  // all reads of buf[cur] done before re-stage
  }

  // ---- row sums across lk groups and the 4 waves of each tile-group ----
  lacc += __shfl_xor(lacc, 16);
  lacc += __shfl_xor(lacc, 32);
  if (lane < 16) ssum[wid * 16 + lane] = lacc;
  __syncthreads();
  const float sc =
      1.0f / (ssum[(tile * 4 + 0) * 16 + lrow] + ssum[(tile * 4 + 1) * 16 + lrow] +
              ssum[(tile * 4 + 2) * 16 + lrow] + ssum[(tile * 4 + 3) * 16 + lrow]);

  // ---- cross-wave cv combine (cvl aliases dead K region) + normalize ----
#pragma unroll
  for (int dd = 0; dd < 4; ++dd)
#pragma unroll
    for (int q = 0; q < 4; ++q)
      cvl[tile * 4224 + ((wq * 16 + lk * 4 + q) * 66) + dd * 16 + lrow] = cvacc[dd][q];
  __syncthreads();
#pragma unroll
  for (int t4 = 0; t4 < 4; ++t4) {
    const int idx = tid + t4 * 512;  // 0..2047
    const int row32 = idx >> 6, dk = idx & 63;
    const int tr = row32 >> 4, row = row32 & 15;
    const float sinv =
        1.0f / (ssum[(tr * 4 + 0) * 16 + row] + ssum[(tr * 4 + 1) * 16 + row] +
                ssum[(tr * 4 + 2) * 16 + row] + ssum[(tr * 4 + 3) * 16 + row]);
    const float v = cvl[tr * 4224 + ((0 * 16 + row) * 66) + dk] +
                    cvl[tr * 4224 + ((1 * 16 + row) * 66) + dk] +
                    cvl[tr * 4224 + ((2 * 16 + row) * 66) + dk] +
                    cvl[tr * 4224 + ((3 * 16 + row) * 66) + dk];
    cvb[(size_t)(b * QL + i0p + row32) * CD + h * DKD + dk] =
        __float2bfloat16(v * sinv);
  }

  // ---- aw epilogue: normalized p -> f32, barrier-free nontemporal stores ----
#pragma unroll
  for (int ii = 0; ii < 32; ++ii) {
    const int cc = ii >> 1, s2 = ii & 1;
    const unsigned short* pp = (const unsigned short*)&pst[ii];
    f32x4 o4;
    o4[0] = bf2f(pp[0]) * sc;
    o4[1] = bf2f(pp[1]) * sc;
    o4[2] = bf2f(pp[2]) * sc;
    o4[3] = bf2f(pp[3]) * sc;
    __builtin_nontemporal_store(
        o4, (f32x4*)(awp + cc * 128 + wq * 32 + s2 * 16 + lk * 4));
  }
}

// ---------------- launcher ----------------

extern "C" void kernel_launch(void* const* d_in, const int* in_sizes, int n_in,
                              void* d_out, int out_size, void* d_ws, size_t ws_size,
                              hipStream_t stream) {
  const float* key = (const float*)d_in[0];
  const float* pos = (const float*)d_in[2];
  const float* ub = (const float*)d_in[4];
  const float* vb = (const float*)d_in[5];
  const float* Wk = (const float*)d_in[6];
  const float* Wv = (const float*)d_in[7];
  const float* Wq = (const float*)d_in[8];
  const float* Wo = (const float*)d_in[9];
  const float* Wp = (const float*)d_in[10];

  char* ws = (char*)d_ws;
  size_t off = 0;
  bf16* keyb = (bf16*)(ws + off); off += (size_t)4096 * 1024 * 2;
  bf16* qsrc = (bf16*)(ws + off); off += (size_t)2048 * 1024 * 2;
  bf16* posb = (bf16*)(ws + off); off += (size_t)2048 * 1024 * 2;
  bf16* wkvb = (bf16*)(ws + off); off += (size_t)2048 * 1024 * 2;
  bf16* wqpb = (bf16*)(ws + off); off += (size_t)2048 * 1024 * 2;
  bf16* wob  = (bf16*)(ws + off); off += (size_t)1024 * 1024 * 2;
  bf16* Kp   = (bf16*)(ws + off); off += (size_t)4096 * 1024 * 2;
  bf16* Vt   = (bf16*)(ws + off); off += (size_t)4096 * 1024 * 2;
  bf16* qu   = (bf16*)(ws + off); off += (size_t)2048 * 1024 * 2;
  bf16* qvb  = (bf16*)(ws + off); off += (size_t)2048 * 1024 * 2;
  bf16* Pbuf = (bf16*)(ws + off); off += (size_t)2048 * 1024 * 2;
  bf16* cvb  = (bf16*)(ws + off); off += (size_t)2048 * 1024 * 2;
  unsigned short* BDsh = (unsigned short*)(ws + off); off += (size_t)32 * QL * KL * 2;  // 128 MB

  float* cv_out = (float*)d_out;
  float* aw_out = (float*)d_out + (size_t)2 * QL * CD;

  // 1. casts (merged)
  cast_all<<<11264, 256, 0, stream>>>(key, pos, Wk, Wv, Wq, Wp, Wo,
                                      keyb, qsrc, posb, wkvb, wqpb, wob);

  // 2. projections
  gemm_bt<4><<<dim3(32, 16), 256, 0, stream>>>(keyb, nullptr, wkvb, Kp, Vt, nullptr,
                                               nullptr, nullptr, 4096, 2048, 1024);
  gemm_bt<5><<<dim3(16, 8, 2), 256, 0, stream>>>(qsrc, posb, wqpb, qu, qvb, Pbuf,
                                                 ub, vb, 2048, 1024, 1024);

  // 3. BD with shifted write
  bd_gemm<<<dim3(8, 16, 32), 256, 0, stream>>>(qvb, Pbuf, BDsh);

  // 4. fused scores + softmax + aw + PV (single-pass, 2 row-tiles per block)
  attn_fused<<<1024, 512, 0, stream>>>(qu, (const unsigned short*)Kp, BDsh,
                                       (const unsigned short*)Vt, aw_out, cvb);

  // 5. output projection
  gemm_bt<1><<<dim3(16, 8), 256, 0, stream>>>(cvb, nullptr, wob, cv_out, nullptr, nullptr,
                                              nullptr, nullptr, 2048, 1024, 1024);
}

// Round 19
// 258.640 us; speedup vs baseline: 1.0197x; 1.0197x over previous
//
#include <hip/hip_runtime.h>
#include <hip/hip_bf16.h>

// Transformer-XL relative multihead attention, MI355X/gfx950.
// B=2, QLEN=1024, MLEN=1024, KLEN=2048, C=1024, H=16, DK=64.
//
// FINAL = round 17 (best measured: 259.6 us). Experiment ledger:
//   r13 base (264.0): counted-vmcnt dbuf pipeline + 40KB LDS pack
//   r14 bd_gemm store-coalescing retile: 268.7 (regressed - barriers)
//   r15 barrier-free loop B, direct V:   280.8 (regressed - V gathers
//       are transaction-bound even L2-resident)
//   r17 2 row-tiles/block shared staging: 259.6 (BEST)
//   r18 single-pass QK+PV fusion (80KB LDS): 263.7 (occupancy 3->2 blk/CU
//       cancelled the phase-count halving)
// Structure:
//   1. cast_all: key->keyb/qsrc + pos/5 weights -> bf16 (one launch)
//   2. gemm<4>: K|V projection (Kp[bh][j][64], Vt[bh][dk][KL])
//      gemm<5>: Q(+u/+v biases) | P projection
//   3. bd_gemm: BDfull[i,c] = qv_i . p_c (K=64 GEMM), written rel-SHIFTED:
//        c >= 1023-i : BDsh[i][i+c-1023]   (d<=1024)
//        else, i>=1  : BDsh[i-1][i+1025+c] (d>=1026)
//      d==1025 never written -> masked at read. BDsh READ-ONLY afterwards.
//   4. attn_fused: XCD-aware grid, 512-thr blocks = 2 row-tiles sharing
//      staged K/V chunks; loop A (QK+exp, vmcnt(3) pipeline), loop B
//      (PV + normalized aw nontemporal stores, vmcnt counts stores).
//   5. gemm<1>: cv = cvb @ Wo^T (f32)
//
// rel_shift closed form (d = j-i):
//   d<=1024 : BD = qv_i  . p_{d+1023}   (main)
//   d==1025 : 0                          (never written; masked at read)
//   d>=1026 : BD = qv_{i+1} . p_{d-1026} (wrap)

typedef __hip_bfloat16 bf16;
typedef __attribute__((ext_vector_type(8))) short bf16x8v;
typedef __attribute__((ext_vector_type(4))) float f32x4;

#define MFMA16(A, B, C) __builtin_amdgcn_mfma_f32_16x16x32_bf16(A, B, C, 0, 0, 0)

#define QL 1024
#define KL 2048
#define NH 16
#define DKD 64
#define CD 1024

static __device__ __forceinline__ unsigned short f2bf(float x) {
  __hip_bfloat16 h = __float2bfloat16(x);
  return __builtin_bit_cast(unsigned short, h);
}
static __device__ __forceinline__ float bf2f(unsigned short u) {
  return __builtin_bit_cast(float, (unsigned)u << 16);
}

typedef const __attribute__((address_space(1))) void* gptr_t;
typedef __attribute__((address_space(3))) void* sptr_t;

// ---------------- merged cast kernel ----------------

__global__ void cast_all(const float* __restrict__ key, const float* __restrict__ pos,
                         const float* __restrict__ wk, const float* __restrict__ wv,
                         const float* __restrict__ wq, const float* __restrict__ wp,
                         const float* __restrict__ wo,
                         bf16* __restrict__ keyb, bf16* __restrict__ qsrc,
                         bf16* __restrict__ posb, bf16* __restrict__ wkvb,
                         bf16* __restrict__ wqpb, bf16* __restrict__ wob) {
  const int bid = blockIdx.x;
  if (bid < 4096) {
    int i = (bid * 256 + threadIdx.x) * 4;
    float4 v = *(const float4*)(key + i);
    ushort4 o;
    o.x = f2bf(v.x); o.y = f2bf(v.y); o.z = f2bf(v.z); o.w = f2bf(v.w);
    *(ushort4*)((unsigned short*)keyb + i) = o;
    int row = i >> 10;
    int col = i & (CD - 1);
    int r2 = row & (KL - 1);
    if (r2 >= QL) {
      int qrow = (row >> 11) * QL + (r2 - QL);
      *(ushort4*)((unsigned short*)qsrc + (size_t)qrow * CD + col) = o;
    }
    return;
  }
  const int mb = bid - 4096;
  const float* src;
  bf16* dst;
  int cb;
  if (mb < 2048)      { src = pos; dst = posb;           cb = mb; }
  else if (mb < 3072) { src = wk;  dst = wkvb;           cb = mb - 2048; }
  else if (mb < 4096) { src = wv;  dst = wkvb + (1<<20); cb = mb - 3072; }
  else if (mb < 5120) { src = wq;  dst = wqpb;           cb = mb - 4096; }
  else if (mb < 6144) { src = wp;  dst = wqpb + (1<<20); cb = mb - 5120; }
  else                { src = wo;  dst = wob;            cb = mb - 6144; }
  int i = cb * 1024 + threadIdx.x * 4;
  float4 v = *(const float4*)(src + i);
  ushort4 o;
  o.x = f2bf(v.x); o.y = f2bf(v.y); o.z = f2bf(v.z); o.w = f2bf(v.w);
  *(ushort4*)((unsigned short*)dst + i) = o;
}

// ---------------- GEMM: C = A @ Bt^T, global_load_lds staging ----------------
// MODE 1: f32 row-major out (O1), stride N
// MODE 4: kv merged: n0<1024 -> Kp[bh][KL][64] (O1); else Vt[bh][dk][KL] (O2)
// MODE 5: z=0: qsrc -> qu/qvb with biases; z=1: posb -> Pbuf (O3)

template <int MODE>
__global__ __launch_bounds__(256) void gemm_bt(
    const bf16* __restrict__ Ain, const bf16* __restrict__ A2,
    const bf16* __restrict__ Btin,
    void* __restrict__ O1, void* __restrict__ O2, void* __restrict__ O3,
    const float* __restrict__ bias1, const float* __restrict__ bias2,
    int M, int N, int K) {
  __shared__ __align__(16) bf16 As[128 * 32];
  __shared__ __align__(16) bf16 Bs[128 * 32];
  const int tid = threadIdx.x;
  const int lane = tid & 63;
  const int wid = tid >> 6;
  const int wr = wid >> 1, wc = wid & 1;
  const int lrow = lane & 15, lk = lane >> 4;
  const int m0 = blockIdx.x * 128, n0 = blockIdx.y * 128;

  const bf16* A = Ain;
  const bf16* Bt = Btin;
  if (MODE == 5) {
    if (blockIdx.z) { A = A2; Bt = Btin + (size_t)(1 << 20); }
  }

  f32x4 acc[4][4];
#pragma unroll
  for (int i = 0; i < 4; i++)
#pragma unroll
    for (int j = 0; j < 4; j++) acc[i][j] = (f32x4){0.f, 0.f, 0.f, 0.f};

  for (int k0 = 0; k0 < K; k0 += 32) {
#pragma unroll
    for (int st = 0; st < 2; ++st) {
      int c = st * 256 + tid;
      __builtin_amdgcn_global_load_lds(
          (gptr_t)(A + (size_t)(m0 + (c >> 2)) * K + k0 + (c & 3) * 8),
          (sptr_t)(As + c * 8), 16, 0, 0);
      __builtin_amdgcn_global_load_lds(
          (gptr_t)(Bt + (size_t)(n0 + (c >> 2)) * K + k0 + (c & 3) * 8),
          (sptr_t)(Bs + c * 8), 16, 0, 0);
    }
    __syncthreads();
    bf16x8v aF[4], bF[4];
#pragma unroll
    for (int s = 0; s < 4; s++) {
      aF[s] = *(const bf16x8v*)(As + (wr * 64 + s * 16 + lrow) * 32 + lk * 8);
      bF[s] = *(const bf16x8v*)(Bs + (wc * 64 + s * 16 + lrow) * 32 + lk * 8);
    }
#pragma unroll
    for (int i = 0; i < 4; i++)
#pragma unroll
      for (int j = 0; j < 4; j++) acc[i][j] = MFMA16(aF[i], bF[j], acc[i][j]);
    __syncthreads();
  }

  const int row0 = m0 + wr * 64 + lk * 4;
  const int col0 = n0 + wc * 64 + lrow;

  if (MODE == 1) {
    float* C = (float*)O1;
#pragma unroll
    for (int i = 0; i < 4; i++)
#pragma unroll
      for (int j = 0; j < 4; j++) {
        int r = row0 + i * 16, c = col0 + j * 16;
#pragma unroll
        for (int q = 0; q < 4; q++) C[(size_t)(r + q) * N + c] = acc[i][j][q];
      }
  } else if (MODE == 4) {
    if (n0 < 1024) {
      // K -> Kp[bh][j][64]
      bf16* C = (bf16*)O1;
#pragma unroll
      for (int i = 0; i < 4; i++)
#pragma unroll
        for (int j = 0; j < 4; j++) {
          int c = col0 + j * 16;
          const int hh = c >> 6, dd = c & 63;
#pragma unroll
          for (int q = 0; q < 4; q++) {
            int m = row0 + i * 16 + q;
            const int bb = m >> 11, jj = m & (KL - 1);
            C[((size_t)(bb * NH + hh) * KL + jj) * DKD + dd] = __float2bfloat16(acc[i][j][q]);
          }
        }
    } else {
      unsigned short* C = (unsigned short*)O2;  // Vt[(b*NH+h)*DKD+dd][KL]
#pragma unroll
      for (int i = 0; i < 4; i++)
#pragma unroll
        for (int j = 0; j < 4; j++) {
          int m = row0 + i * 16;
          int c = col0 + j * 16 - 1024;
          int bb = m >> 11;
          int jj = m & (KL - 1);
          int bhh = bb * NH + (c >> 6);
          int dd = c & (DKD - 1);
          ushort4 o;
          o.x = f2bf(acc[i][j][0]); o.y = f2bf(acc[i][j][1]);
          o.z = f2bf(acc[i][j][2]); o.w = f2bf(acc[i][j][3]);
          *(ushort4*)(C + (size_t)(bhh * DKD + dd) * KL + jj) = o;
        }
    }
  } else {  // MODE 5
    if (blockIdx.z == 0) {
      bf16* C1 = (bf16*)O1;
      bf16* C2 = (bf16*)O2;
#pragma unroll
      for (int i = 0; i < 4; i++)
#pragma unroll
        for (int j = 0; j < 4; j++) {
          int r = row0 + i * 16, c = col0 + j * 16;
          float b1 = bias1[c], b2 = bias2[c];
#pragma unroll
          for (int q = 0; q < 4; q++) {
            float v = acc[i][j][q];
            C1[(size_t)(r + q) * CD + c] = __float2bfloat16(v + b1);
            C2[(size_t)(r + q) * CD + c] = __float2bfloat16(v + b2);
          }
        }
    } else {
      bf16* C = (bf16*)O3;
#pragma unroll
      for (int i = 0; i < 4; i++)
#pragma unroll
        for (int j = 0; j < 4; j++) {
          int r = row0 + i * 16, c = col0 + j * 16;
#pragma unroll
          for (int q = 0; q < 4; q++) C[(size_t)(r + q) * CD + c] = __float2bfloat16(acc[i][j][q]);
        }
    }
  }
}

// ---------------- BD gemm with shifted write ----------------
// BDfull[i,c] = qv[b,i,h,:] . Pb[c,h,:]  (K=64). grid (8, 16, 32), block 256.

__global__ __launch_bounds__(256) void bd_gemm(
    const bf16* __restrict__ qvb, const bf16* __restrict__ Pbuf,
    unsigned short* __restrict__ BDsh) {
  __shared__ __align__(16) bf16 As[128 * 32];
  __shared__ __align__(16) bf16 Bs[128 * 32];
  const int tid = threadIdx.x;
  const int lane = tid & 63;
  const int wid = tid >> 6;
  const int wr = wid >> 1, wc = wid & 1;
  const int lrow = lane & 15, lk = lane >> 4;
  const int m0 = blockIdx.x * 128, n0 = blockIdx.y * 128;
  const int bh = blockIdx.z, b = bh >> 4, h = bh & 15;

  const bf16* A = qvb + (size_t)(b * QL + m0) * CD + h * DKD;
  const bf16* Bt = Pbuf + (size_t)n0 * CD + h * DKD;

  f32x4 acc[4][4];
#pragma unroll
  for (int i = 0; i < 4; i++)
#pragma unroll
    for (int j = 0; j < 4; j++) acc[i][j] = (f32x4){0.f, 0.f, 0.f, 0.f};

#pragma unroll
  for (int k0 = 0; k0 < 64; k0 += 32) {
#pragma unroll
    for (int st = 0; st < 2; ++st) {
      int c = st * 256 + tid;
      __builtin_amdgcn_global_load_lds(
          (gptr_t)(A + (size_t)(c >> 2) * CD + k0 + (c & 3) * 8),
          (sptr_t)(As + c * 8), 16, 0, 0);
      __builtin_amdgcn_global_load_lds(
          (gptr_t)(Bt + (size_t)(c >> 2) * CD + k0 + (c & 3) * 8),
          (sptr_t)(Bs + c * 8), 16, 0, 0);
    }
    __syncthreads();
    bf16x8v aF[4], bF[4];
#pragma unroll
    for (int s = 0; s < 4; s++) {
      aF[s] = *(const bf16x8v*)(As + (wr * 64 + s * 16 + lrow) * 32 + lk * 8);
      bF[s] = *(const bf16x8v*)(Bs + (wc * 64 + s * 16 + lrow) * 32 + lk * 8);
    }
#pragma unroll
    for (int i = 0; i < 4; i++)
#pragma unroll
      for (int j = 0; j < 4; j++) acc[i][j] = MFMA16(aF[i], bF[j], acc[i][j]);
    __syncthreads();
  }

  unsigned short* out = BDsh + (size_t)bh * QL * KL;
  const int row0 = m0 + wr * 64 + lk * 4;
  const int col0 = n0 + wc * 64 + lrow;
#pragma unroll
  for (int i = 0; i < 4; i++)
#pragma unroll
    for (int j = 0; j < 4; j++) {
      const int cg = col0 + j * 16;
#pragma unroll
      for (int q = 0; q < 4; q++) {
        const int il = row0 + i * 16 + q;  // 0..1023
        const int thr = 1023 - il;
        unsigned short val = f2bf(acc[i][j][q]);
        if (cg >= thr) {
          out[(size_t)il * KL + (cg - thr)] = val;            // d <= 1024
        } else if (il >= 1) {
          out[(size_t)(il - 1) * KL + il + 1025 + cg] = val;  // d >= 1026
        }
      }
    }
}

// ---------------- fused score + softmax + aw + PV kernel ----------------
// 1-D grid 1024, XCD-aware decode. Block 512 = 8 waves = 2 tile-groups of 4;
// tile-group t handles rows [pair*32 + t*16, +16). Staged K/V chunks shared
// between both tile-groups. 16 chunks of 128 cols; per chunk wave-in-group wq
// owns cols [wq*32,(wq+1)*32).
// LDS = 49664 B, manual aliasing:
//   loop A: K dbuf @0 (2x16384), BD dbuf @32768 (2x8192), ssum @49152 (512)
//   loop B: V dbuf @0 (reuses K), pt @32768 (2x5120)
//   post:   cv @0 (2x16896)

__global__ __launch_bounds__(512) void attn_fused(
    const bf16* __restrict__ qu, const unsigned short* __restrict__ Kp,
    const unsigned short* __restrict__ BDsh, const unsigned short* __restrict__ Vt,
    float* __restrict__ aw, bf16* __restrict__ cvb) {
  __shared__ __align__(16) char smraw[49664];
  float* ssum = (float*)(smraw + 49152);                  // [8][16]
  unsigned short* pt = (unsigned short*)(smraw + 32768);  // [2][4][16][40]
  float* cvl = (float*)smraw;                             // [2][4][16][66]

  const int bid = blockIdx.x;
  const int xcd = bid & 7;
  const int kk = bid >> 3;           // 0..127
  const int bh = xcd * 4 + (kk >> 5);
  const int pair = kk & 31;
  const int i0p = pair * 32;
  const int b = bh >> 4, h = bh & 15;
  const int tid = threadIdx.x;
  const int lane = tid & 63, wid = tid >> 6;
  const int tile = wid >> 2, wq = wid & 3;
  const int lrow = lane & 15, lk = lane >> 4;
  const int i0 = i0p + tile * 16;
  const int irow = i0 + lrow;

  const size_t qoff = (size_t)(b * QL + irow) * CD + h * DKD + lk * 8;
  const bf16x8v quF0 = *(const bf16x8v*)(qu + qoff);
  const bf16x8v quF1 = *(const bf16x8v*)(qu + qoff + 32);

  const unsigned short* Kph = Kp + (size_t)bh * KL * DKD;             // [j][64]
  const unsigned short* BDrow = BDsh + (size_t)(bh * QL + i0p) * KL;  // 32 rows
  const unsigned short* Vth = Vt + (size_t)bh * DKD * KL;             // [dk][KL]
  float* awp = aw + (size_t)(bh * QL + irow) * KL;

  ushort4 pst[32];
  float lacc = 0.f;

  // stageA: K chunk (128 rows x 128B = 16KB, 2 loads/thr) + BD band chunk
  // (32 rows x 256B = 8KB, 1 load/thr) -> 3 loads/thread.
  auto stageA = [&](int cc, int bsel) {
#pragma unroll
    for (int st = 0; st < 2; ++st) {
      const int pos = (st * 512 + tid) * 16;
      const int krow = pos >> 7;
      const int kb = (pos & 127) ^ ((krow & 7) << 4);
      __builtin_amdgcn_global_load_lds(
          (gptr_t)(Kph + (size_t)(cc * 128 + krow) * DKD + (kb >> 1)),
          (sptr_t)(smraw + bsel * 16384 + pos), 16, 0, 0);
    }
    {
      const int pos = tid * 16;
      const int brow = pos >> 8;  // 0..31
      const int bb2 = (pos & 255) ^ ((brow & 7) << 4);
      __builtin_amdgcn_global_load_lds(
          (gptr_t)(BDrow + (size_t)brow * KL + cc * 128 + (bb2 >> 1)),
          (sptr_t)(smraw + 32768 + bsel * 8192 + pos), 16, 0, 0);
    }
  };

  // stageV: V chunk (64 rows x 256B = 16KB) -> 2 loads/thread.
  auto stageV = [&](int cc, int bsel) {
#pragma unroll
    for (int st = 0; st < 2; ++st) {
      const int pos = (st * 512 + tid) * 16;
      const int vrow = pos >> 8;
      const int vb = (pos & 255) ^ ((vrow & 7) << 4);
      __builtin_amdgcn_global_load_lds(
          (gptr_t)(Vth + (size_t)vrow * KL + cc * 128 + (vb >> 1)),
          (sptr_t)(smraw + bsel * 16384 + pos), 16, 0, 0);
    }
  };

  // ---- loop A: K+BD -> p_un (pipelined, counted vmcnt) ----
  stageA(0, 0);
#pragma unroll
  for (int c = 0; c < 16; ++c) {
    const int cur = c & 1;
    if (c < 15) {
      stageA(c + 1, cur ^ 1);
      asm volatile("s_waitcnt vmcnt(3)" ::: "memory");
    } else {
      asm volatile("s_waitcnt vmcnt(0)" ::: "memory");
    }
    __builtin_amdgcn_sched_barrier(0);
    __builtin_amdgcn_s_barrier();

    const char* Kc = (const char*)smraw + cur * 16384;
    const char* BDc = (const char*)smraw + 32768 + cur * 8192;
#pragma unroll
    for (int s2 = 0; s2 < 2; ++s2) {
      const int jloc = wq * 32 + s2 * 16 + lrow;
      const int sw = (jloc & 7) << 4;
      const bf16x8v kF0 = *(const bf16x8v*)(Kc + jloc * 128 + ((lk * 16) ^ sw));
      const bf16x8v kF1 = *(const bf16x8v*)(Kc + jloc * 128 + ((64 + lk * 16) ^ sw));
      f32x4 ac = (f32x4){0.f, 0.f, 0.f, 0.f};
      __builtin_amdgcn_s_setprio(1);
      ac = MFMA16(kF0, quF0, ac);  // swapped: out row = j-local, col = i-local
      ac = MFMA16(kF1, quF1, ac);
      __builtin_amdgcn_s_setprio(0);

      const int bdb = (tile * 16 + lrow) * 256 +
                      ((wq * 64 + s2 * 32 + lk * 8) ^ ((lrow & 7) << 4));
      const ushort4 bd4 = *(const ushort4*)(BDc + bdb);
      const unsigned short* bdp = (const unsigned short*)&bd4;
      ushort4 pb;
      unsigned short* pp = (unsigned short*)&pb;
#pragma unroll
      for (int q = 0; q < 4; ++q) {
        const int jcol = c * 128 + wq * 32 + s2 * 16 + lk * 4 + q;
        const float bd = (jcol - irow == 1025) ? 0.f : bf2f(bdp[q]);
        const float pu = __expf((ac[q] + bd) * 0.125f);
        lacc += pu;
        pp[q] = f2bf(pu);
      }
      pst[c * 2 + s2] = pb;
    }
    __builtin_amdgcn_s_barrier();  // all reads of buf[cur] done before re-stage
  }

  // ---- row sums across lk groups and the 4 waves of each tile-group ----
  lacc += __shfl_xor(lacc, 16);
  lacc += __shfl_xor(lacc, 32);
  if (lane < 16) ssum[wid * 16 + lane] = lacc;
  __syncthreads();
  const float sc =
      1.0f / (ssum[(tile * 4 + 0) * 16 + lrow] + ssum[(tile * 4 + 1) * 16 + lrow] +
              ssum[(tile * 4 + 2) * 16 + lrow] + ssum[(tile * 4 + 3) * 16 + lrow]);
  __syncthreads();  // ssum consumed before V staging begins

  // ---- loop B: V -> PV + normalized aw stores (pipelined; stores counted) ----
  f32x4 cvacc[4];
#pragma unroll
  for (int dd = 0; dd < 4; ++dd) cvacc[dd] = (f32x4){0.f, 0.f, 0.f, 0.f};

  unsigned short* ptw = pt + ((tile * 4 + wq) * 16 + lrow) * 40;

  stageV(0, 0);
#pragma unroll
  for (int c = 0; c < 16; ++c) {
    const int cur = c & 1;
    if (c < 15) stageV(c + 1, cur ^ 1);
    // vmcnt: need V(c)'s 2 loads done. Issue order: V(c)x2, st(c-1)x2, V(c+1)x2.
    //   c==0: V(1)x2 -> 2 ; 0<c<15: st(c-1)x2 + V(c+1)x2 -> 4 ; c==15: st(14)x2 -> 2
    if (c == 0)      asm volatile("s_waitcnt vmcnt(2)" ::: "memory");
    else if (c < 15) asm volatile("s_waitcnt vmcnt(4)" ::: "memory");
    else             asm volatile("s_waitcnt vmcnt(2)" ::: "memory");
    __builtin_amdgcn_sched_barrier(0);
    __builtin_amdgcn_s_barrier();

#pragma unroll
    for (int s2 = 0; s2 < 2; ++s2) {
      const unsigned short* pp = (const unsigned short*)&pst[c * 2 + s2];
      const float p0 = bf2f(pp[0]) * sc;
      const float p1 = bf2f(pp[1]) * sc;
      const float p2 = bf2f(pp[2]) * sc;
      const float p3 = bf2f(pp[3]) * sc;
      f32x4 o4 = (f32x4){p0, p1, p2, p3};
      __builtin_nontemporal_store(
          o4, (f32x4*)(awp + c * 128 + wq * 32 + s2 * 16 + lk * 4));
      ushort4 pb2;
      pb2.x = f2bf(p0); pb2.y = f2bf(p1); pb2.z = f2bf(p2); pb2.w = f2bf(p3);
      *(ushort4*)(ptw + s2 * 16 + lk * 4) = pb2;
    }
    const bf16x8v aF = *(const bf16x8v*)(ptw + lk * 8);
    const char* Vc = (const char*)smraw + cur * 16384;
    __builtin_amdgcn_s_setprio(1);
#pragma unroll
    for (int dd = 0; dd < 4; ++dd) {
      const int vr = dd * 16 + lrow;
      const bf16x8v vF =
          *(const bf16x8v*)(Vc + vr * 256 + ((wq * 64 + lk * 16) ^ ((vr & 7) << 4)));
      cvacc[dd] = MFMA16(aF, vF, cvacc[dd]);
    }
    __builtin_amdgcn_s_setprio(0);
    __builtin_amdgcn_s_barrier();
  }

  // ---- cross-wave cv combine (per tile-group; cv aliases dead V region) ----
#pragma unroll
  for (int dd = 0; dd < 4; ++dd)
#pragma unroll
    for (int q = 0; q < 4; ++q)
      cvl[tile * 4224 + ((wq * 16 + lk * 4 + q) * 66) + dd * 16 + lrow] = cvacc[dd][q];
  __syncthreads();
#pragma unroll
  for (int t4 = 0; t4 < 4; ++t4) {
    const int idx = tid + t4 * 512;          // 0..2047
    const int row32 = idx >> 6, dk = idx & 63;
    const int tr = row32 >> 4, row = row32 & 15;
    const float v = cvl[tr * 4224 + ((0 * 16 + row) * 66) + dk] +
                    cvl[tr * 4224 + ((1 * 16 + row) * 66) + dk] +
                    cvl[tr * 4224 + ((2 * 16 + row) * 66) + dk] +
                    cvl[tr * 4224 + ((3 * 16 + row) * 66) + dk];
    cvb[(size_t)(b * QL + i0p + row32) * CD + h * DKD + dk] = __float2bfloat16(v);
  }
}

// ---------------- launcher ----------------

extern "C" void kernel_launch(void* const* d_in, const int* in_sizes, int n_in,
                              void* d_out, int out_size, void* d_ws, size_t ws_size,
                              hipStream_t stream) {
  const float* key = (const float*)d_in[0];
  const float* pos = (const float*)d_in[2];
  const float* ub = (const float*)d_in[4];
  const float* vb = (const float*)d_in[5];
  const float* Wk = (const float*)d_in[6];
  const float* Wv = (const float*)d_in[7];
  const float* Wq = (const float*)d_in[8];
  const float* Wo = (const float*)d_in[9];
  const float* Wp = (const float*)d_in[10];

  char* ws = (char*)d_ws;
  size_t off = 0;
  bf16* keyb = (bf16*)(ws + off); off += (size_t)4096 * 1024 * 2;
  bf16* qsrc = (bf16*)(ws + off); off += (size_t)2048 * 1024 * 2;
  bf16* posb = (bf16*)(ws + off); off += (size_t)2048 * 1024 * 2;
  bf16* wkvb = (bf16*)(ws + off); off += (size_t)2048 * 1024 * 2;
  bf16* wqpb = (bf16*)(ws + off); off += (size_t)2048 * 1024 * 2;
  bf16* wob  = (bf16*)(ws + off); off += (size_t)1024 * 1024 * 2;
  bf16* Kp   = (bf16*)(ws + off); off += (size_t)4096 * 1024 * 2;
  bf16* Vt   = (bf16*)(ws + off); off += (size_t)4096 * 1024 * 2;
  bf16* qu   = (bf16*)(ws + off); off += (size_t)2048 * 1024 * 2;
  bf16* qvb  = (bf16*)(ws + off); off += (size_t)2048 * 1024 * 2;
  bf16* Pbuf = (bf16*)(ws + off); off += (size_t)2048 * 1024 * 2;
  bf16* cvb  = (bf16*)(ws + off); off += (size_t)2048 * 1024 * 2;
  unsigned short* BDsh = (unsigned short*)(ws + off); off += (size_t)32 * QL * KL * 2;  // 128 MB

  float* cv_out = (float*)d_out;
  float* aw_out = (float*)d_out + (size_t)2 * QL * CD;

  // 1. casts (merged)
  cast_all<<<11264, 256, 0, stream>>>(key, pos, Wk, Wv, Wq, Wp, Wo,
                                      keyb, qsrc, posb, wkvb, wqpb, wob);

  // 2. projections
  gemm_bt<4><<<dim3(32, 16), 256, 0, stream>>>(keyb, nullptr, wkvb, Kp, Vt, nullptr,
                                               nullptr, nullptr, 4096, 2048, 1024);
  gemm_bt<5><<<dim3(16, 8, 2), 256, 0, stream>>>(qsrc, posb, wqpb, qu, qvb, Pbuf,
                                                 ub, vb, 2048, 1024, 1024);

  // 3. BD with shifted write
  bd_gemm<<<dim3(8, 16, 32), 256, 0, stream>>>(qvb, Pbuf, BDsh);

  // 4. fused scores + softmax + aw + PV (2 row-tiles per block, shared staging)
  attn_fused<<<1024, 512, 0, stream>>>(qu, (const unsigned short*)Kp, BDsh,
                                       (const unsigned short*)Vt, aw_out, cvb);

  // 5. output projection
  gemm_bt<1><<<dim3(16, 8), 256, 0, stream>>>(cvb, nullptr, wob, cv_out, nullptr, nullptr,
                                              nullptr, nullptr, 2048, 1024, 1024);
}